// Round 7
// baseline (461.272 us; speedup 1.0000x reference)
//
#include <hip/hip_runtime.h>
#include <hip/hip_bf16.h>
#include <hip/hip_fp16.h>
#include <cstdint>
#include <cstddef>

typedef unsigned short u16;
typedef __attribute__((ext_vector_type(8))) short bf16x8;
typedef __attribute__((ext_vector_type(8))) _Float16 f16x8;
typedef __attribute__((ext_vector_type(4))) float f32x4;

#define MFMA16(a,b,c)  __builtin_amdgcn_mfma_f32_16x16x32_bf16((a),(b),(c),0,0,0)
#define MFMAF16(a,b,c) __builtin_amdgcn_mfma_f32_16x16x32_f16((a),(b),(c),0,0,0)

// B=2 T=16 H=W=56 C=128  HW=3136  N=100352  HID=512
// GP/HP (f16) layout: [b][cg32][hw3136][cl4][t16]  (t contiguous, 32B per (hw,cl))
//   u16 idx = (((b*32+cg)*3136 + hw)*4 + cl)*16 + t          slab = 200704 u16/(b,cg)
// ELH (bf16) layout: (((b*32+cg)*16 + t)*3136 + hw)*4 + cl
// CIRG/CIRH (f16 MFMA B-frags of temporal circulants, taps paired 2-per-MFMA):
//   u32 idx = ((c*25 + tp)*64 + lane)*4 + uu      (16B per lane per tap-pair)

static __device__ __forceinline__ float b2f(u16 u){ return __uint_as_float(((unsigned)u)<<16); }
static __device__ __forceinline__ u16 f2b(float f){
  unsigned u = __float_as_uint(f);
  return (u16)((u + 0x7fffu + ((u>>16)&1u)) >> 16);
}
static __device__ __forceinline__ u16 f2h(float f){ return __half_as_ushort(__float2half(f)); }

union U4F { uint4 u; f16x8 h; };

// async global->LDS 16B: LDS dest = wave-uniform base + lane*16, global src per-lane
static __device__ __forceinline__ void gld_lds16(const void* g, void* l){
  __builtin_amdgcn_global_load_lds(
      (const __attribute__((address_space(1))) void*)g,
      (__attribute__((address_space(3))) void*)l, 16, 0, 0);
}

// dtype detector: sample 64 even-index u16 words of x. bf16 N(0,1) data -> exponent
// field in [100,140] essentially always; f32 -> mantissa halves, ~uniform exponent.
static __device__ __forceinline__ bool input_is_f32(const void* xp){
  const u16* u = (const u16*)xp;
  int cnt = 0;
#pragma unroll
  for (int i = 0; i < 64; ++i){
    unsigned e = (u[2*i] >> 7) & 0xFF;
    cnt += (e >= 100 && e <= 140) ? 1 : 0;
  }
  return cnt < 32;
}

static __device__ __forceinline__ u16 ldb(const void* p, int i, bool f32){
  return f32 ? f2b(((const float*)p)[i]) : ((const u16*)p)[i];
}
static __device__ __forceinline__ float ldf(const void* p, int i, bool f32){
  return f32 ? ((const float*)p)[i] : b2f(((const u16*)p)[i]);
}

// ---------------- K0: canonicalize inputs (+ transposes + circulant B-frag build) ----------------
__global__ __launch_bounds__(256) void k0_prep(
    const void* __restrict__ x,
    const void* __restrict__ Wg, const void* __restrict__ Wh, const void* __restrict__ Wo,
    const void* __restrict__ W1, const void* __restrict__ W2,
    const void* __restrict__ gk, const void* __restrict__ hk,
    const void* __restrict__ bg, const void* __restrict__ bh, const void* __restrict__ bo,
    const void* __restrict__ lns, const void* __restrict__ lnb,
    const void* __restrict__ b1, const void* __restrict__ b2, const void* __restrict__ gm,
    u16* __restrict__ XB,
    u16* __restrict__ WgT, u16* __restrict__ WhT, u16* __restrict__ WoT,
    u16* __restrict__ W1T, u16* __restrict__ W2T,
    unsigned* __restrict__ CIRG, unsigned* __restrict__ CIRH, u16* __restrict__ PRM)
{
  const bool f32 = input_is_f32(x);
  int tid = blockIdx.x*blockDim.x + threadIdx.x;
  int np  = gridDim.x*blockDim.x;

  // x -> XB (bf16), 2 elements per u32 store
  if (f32){
    const float* xf = (const float*)x;
    for (int p = tid; p < 6422528; p += np){
      unsigned v = (unsigned)f2b(xf[2*p]) | ((unsigned)f2b(xf[2*p+1]) << 16);
      ((unsigned*)XB)[p] = v;
    }
  } else {
    const unsigned* xu = (const unsigned*)x;
    for (int p = tid; p < 6422528; p += np) ((unsigned*)XB)[p] = xu[p];
  }

  for (int p = tid; p < 16384; p += np){           // 128x128 transposes
    int n = p>>7, k = p&127;
    WgT[p] = ldb(Wg, k*128+n, f32);
    WhT[p] = ldb(Wh, k*128+n, f32);
    WoT[p] = ldb(Wo, k*128+n, f32);
  }
  for (int p = tid; p < 65536; p += np){           // W1 (128,512) -> W1T (512,128)
    int n = p>>7, k = p&127;
    W1T[p] = ldb(W1, k*512+n, f32);
  }
  for (int p = tid; p < 65536; p += np){           // W2 (512,128) -> W2T (128,512)
    int n = p>>9, k = p&511;
    W2T[p] = ldb(W2, k*128+n, f32);
  }

  // circulant B-fragments for mfma_f32_16x16x32_f16:
  //   B[k][n]: n = t_out (lane&15), k = (lane>>4)*8 + jj; tap-pair tp: spatial tap
  //   tapA = 2tp (k<16), tapB = 2tp+1 (k>=16, zero-padded at tp=24).
  //   B[k][n] = w[c][tap][(n - t_in + 2) mod 16] if that temporal idx < 5 else 0,
  //   with t_in = (k&15). gate/hidden kernel layout (C,5,7,7): w = gk[c*245 + i*49 + tap]
  for (int p = tid; p < 819200; p += np){
    int uu = p & 3;
    int lane = (p >> 2) & 63;
    int tpc = p >> 8;                 // c*25 + tp
    int c = tpc / 25, tp = tpc - c*25;
    int qq = lane >> 4, nn = lane & 15;
    int tap = 2*tp + (qq >> 1);
    unsigned vg = 0, vh = 0;
    if (tap < 49){
      int kk = ((qq & 1) << 3) + uu*2;          // t_in of low f16
      int i0 = (nn - kk + 2) & 15;
      int i1 = (nn - kk + 1) & 15;              // t_in + 1
      unsigned g0 = (i0 < 5) ? (unsigned)f2h(ldf(gk, c*245 + i0*49 + tap, f32)) : 0u;
      unsigned h0 = (i0 < 5) ? (unsigned)f2h(ldf(hk, c*245 + i0*49 + tap, f32)) : 0u;
      unsigned g1 = (i1 < 5) ? (unsigned)f2h(ldf(gk, c*245 + i1*49 + tap, f32)) : 0u;
      unsigned h1 = (i1 < 5) ? (unsigned)f2h(ldf(hk, c*245 + i1*49 + tap, f32)) : 0u;
      vg = g0 | (g1 << 16);
      vh = h0 | (h1 << 16);
    }
    CIRG[p] = vg; CIRH[p] = vh;
  }

  // param block (bf16): bg@0 bh@128 bo@256 lns@384 lnb@512 b1@640 b2@1152 gamma@1280
  for (int p = tid; p < 1408; p += np){
    const void* src; int off;
    if      (p < 128)  { src = bg;  off = p; }
    else if (p < 256)  { src = bh;  off = p-128; }
    else if (p < 384)  { src = bo;  off = p-256; }
    else if (p < 512)  { src = lns; off = p-384; }
    else if (p < 640)  { src = lnb; off = p-512; }
    else if (p < 1152) { src = b1;  off = p-640; }
    else if (p < 1280) { src = b2;  off = p-1152; }
    else               { src = gm;  off = p-1280; }
    PRM[p] = ldb(src, off, f32);
  }
}

// ---------------- K1: dual GEMM  gate = x@Wg+bg, hidden = x@Wh+bh (f16 out, t-contiguous) ----------------
__global__ __launch_bounds__(256) void k1_dualgemm(
    const u16* __restrict__ XB, const u16* __restrict__ WgT, const u16* __restrict__ WhT,
    const u16* __restrict__ PRM,
    u16* __restrict__ GP, u16* __restrict__ HP)
{
  int bid = blockIdx.x;                  // 1568 = 2b * 784 hw-groups
  int b = bid / 784; int hw = (bid % 784)*4 + (threadIdx.x >> 6);
  int lane = threadIdx.x & 63;
  int lrow = lane & 15, q = lane >> 4;

  bf16x8 a[4];   // A row (in-tile) = lrow = t; k-cols q*8 + kt*32
  const u16* xr = XB + ((size_t)(b*16 + lrow)*3136 + hw)*128 + q*8;
#pragma unroll
  for (int kt = 0; kt < 4; ++kt) a[kt] = *(const bf16x8*)(xr + kt*32);

#pragma unroll
  for (int mat = 0; mat < 2; ++mat){
    const u16* WT  = mat ? WhT : WgT;
    const u16* bia = PRM + (mat ? 128 : 0);
    u16* out       = mat ? HP  : GP;
#pragma unroll
    for (int nt = 0; nt < 8; ++nt){
      f32x4 acc = {0.f,0.f,0.f,0.f};
      const u16* wr = WT + (nt*16 + lrow)*128 + q*8;
#pragma unroll
      for (int kt = 0; kt < 4; ++kt){
        bf16x8 bfr = *(const bf16x8*)(wr + kt*32);
        acc = MFMA16(a[kt], bfr, acc);
      }
      int c = nt*16 + lrow;              // C col = output channel
      float bv = b2f(bia[c]);
      size_t base = (((size_t)(b*32 + (c>>2))*3136 + hw)*4 + (c&3))*16 + q*4;
      ushort4 pk;
      pk.x = f2h(acc[0] + bv); pk.y = f2h(acc[1] + bv);
      pk.z = f2h(acc[2] + bv); pk.w = f2h(acc[3] + bv);
      *(ushort4*)(out + base) = pk;      // t = q*4 .. q*4+3
    }
  }
}

// ---------------- K2: circular 5x7x7 depthwise conv via MFMA circulants + linear scan ----------------
__global__ __launch_bounds__(256, 5) void k2_conv_scan(
    const u16* __restrict__ GP, const u16* __restrict__ HP,
    const u16* __restrict__ CIRG, const u16* __restrict__ CIRH,
    u16* __restrict__ ELH)
{
  __shared__ __align__(16) unsigned su[6272];   // 25,088 B

  int bid = blockIdx.x;                    // 3136 = 2 * 32 * 49
  int b = bid / 1568; int rr = bid - b*1568;
  int cg = rr / 49; int s = rr % 49;
  int th = s / 7, tw = s % 7;
  int tid = threadIdx.x;
  int h0g = th*8, w0g = tw*8;
  size_t tb = (size_t)(b*32 + cg)*200704;  // u16 slab base (GP/HP/ELH identical value)

  int wv = tid >> 6, lane = tid & 63;
  int q = lane >> 4, lrow = lane & 15;
  int hb = lrow >> 3, wb = lrow & 7;       // spatial of A-row at m=0: h=hb, w=wb

  int cu = __builtin_amdgcn_readfirstlane(cg*4 + wv);
  const u16* cirg = CIRG + (size_t)cu*12800;   // 25 tp * 64 lane * 8 u16
  const u16* cirh = CIRH + (size_t)cu*12800;

  // ---- staging chunk offsets: chunk ci = cl*392 + pos*2 + half  (LDS addr = ci*16, linear) ----
  unsigned soff[7]; bool sval[7];
#pragma unroll
  for (int ss = 0; ss < 7; ++ss){
    int ci = ss*256 + tid;
    sval[ss] = (ci < 1568);
    int clc = ci / 392;
    int rem = ci - clc*392;
    int pos = rem >> 1, half = rem & 1;
    int hh = pos / 14, ww = pos - hh*14;
    int hg = h0g + hh - 3; if (hg < 0) hg += 56; else if (hg >= 56) hg -= 56;
    int wg = w0g + ww - 3; if (wg < 0) wg += 56; else if (wg >= 56) wg -= 56;
    soff[ss] = (unsigned)((hg*56 + wg)*128 + clc*32 + half*16);
  }
  const char* gpb = (const char*)(GP + tb);
  const char* hpb = (const char*)(HP + tb);

  auto stagepass = [&](const char* Pb){
#pragma unroll
    for (int ss = 0; ss < 7; ++ss){
      if (sval[ss])
        gld_lds16(Pb + soff[ss], (char*)su + (ss*256 + wv*64)*16);
    }
  };

  auto convpass = [&](const u16* cir, f32x4* acc){
#pragma unroll
    for (int m = 0; m < 4; ++m) acc[m] = (f32x4){0.f,0.f,0.f,0.f};
    U4F bq0, bq1, bq2;
    bq0.u = *(const uint4*)(cir + 0*512 + lane*8);
    bq1.u = *(const uint4*)(cir + 1*512 + lane*8);
    bq2.u = *(const uint4*)(cir + 2*512 + lane*8);
    const int base_cl = wv*6272;
#pragma unroll
    for (int tp = 0; tp < 25; ++tp){
      const int tA = 2*tp;
      const int tB = (2*tp + 1 > 48) ? 48 : 2*tp + 1;
      const int dhA = 6 - tA/7, dwA = 6 - tA%7;
      const int dhB = 6 - tB/7, dwB = 6 - tB%7;
      int dh = (q >= 2) ? dhB : dhA;
      int dw = (q >= 2) ? dwB : dwA;
      const char* sp = (const char*)su +
          (base_cl + ((hb + dh)*14 + (wb + dw))*32 + (q & 1)*16);
      U4F a0, a1, a2, a3;
      a0.u = *(const uint4*)(sp);
      a1.u = *(const uint4*)(sp + 896);    // m=1: h += 2 -> pos += 28
      a2.u = *(const uint4*)(sp + 1792);
      a3.u = *(const uint4*)(sp + 2688);
      f16x8 bb = (tp % 3 == 0) ? bq0.h : (tp % 3 == 1) ? bq1.h : bq2.h;
      acc[0] = MFMAF16(a0.h, bb, acc[0]);
      acc[1] = MFMAF16(a1.h, bb, acc[1]);
      acc[2] = MFMAF16(a2.h, bb, acc[2]);
      acc[3] = MFMAF16(a3.h, bb, acc[3]);
      if (tp + 3 < 25){
        uint4 nb = *(const uint4*)(cir + (tp+3)*512 + lane*8);
        if (tp % 3 == 0) bq0.u = nb; else if (tp % 3 == 1) bq1.u = nb; else bq2.u = nb;
      }
    }
  };

  f32x4 accG[4], accH[4];
  stagepass(gpb);
  __syncthreads();          // gld_lds data resident
  convpass(cirg, accG);
  __syncthreads();          // conv reads done before restage overwrites
  stagepass(hpb);
  __syncthreads();
  convpass(cirh, accH);

  // ---- pointwise (linear-space) ----
  float fv[16], vv[16];
#pragma unroll
  for (int e = 0; e < 16; ++e){
    float g  = accG[e>>2][e&3];
    float hc = accH[e>>2][e&3];
    float eg = __expf(g);
    float fr = __builtin_amdgcn_rcpf(1.f + eg);   // 1 - z = sigmoid(-g)
    float zz = 1.f - fr;                          // z = sigmoid(g), inf-safe
    fv[e] = fr;
    vv[e] = (hc*hc + 1e-6f) * zz;
  }
  // ---- inclusive scan over t (= lrow) within 16-lane groups ----
#pragma unroll
  for (int d = 1; d < 16; d <<= 1){
    bool ok = (lrow >= d);
#pragma unroll
    for (int e = 0; e < 16; ++e){
      float Lf = __shfl_up(fv[e], (unsigned)d, 16);
      float Lv = __shfl_up(vv[e], (unsigned)d, 16);
      Lf = ok ? Lf : 1.f;
      Lv = ok ? Lv : 0.f;
      vv[e] = fmaf(fv[e], Lv, vv[e]);
      fv[e] = fv[e] * Lf;
    }
  }
  // ---- store h = vv (bf16) ----
  size_t ob = tb + (size_t)lrow*12544 + (size_t)(h0g*56 + w0g)*4 + wv;
#pragma unroll
  for (int e = 0; e < 16; ++e){
    int r = (e>>2)*16 + q*4 + (e&3);
    ELH[ob + (size_t)((r>>3)*56 + (r&7))*4] = f2b(vv[e]);
  }
}

// ---------------- K34 v5: dual-tile M=128, W streamed from global (L2-resident), ZERO barriers ----------------
// LDS = sXp (persists, never aliased) + per-wave sH scratch = 53,248 B -> 3 blocks/CU (12 waves).
// Phase B: W1/W2 fragments read directly from global, each shared between tiles A and B.
// No sW staging => no vmcnt convoys, no __syncthreads anywhere (all LDS is same-wave-ordered).
__global__ __launch_bounds__(256, 4) void k34_gemm_ln_mlp(
    const u16* __restrict__ ELH, const u16* __restrict__ WoT,
    const u16* __restrict__ W1T, const u16* __restrict__ W2T,
    const u16* __restrict__ PRM,
    const void* __restrict__ xraw, void* __restrict__ outv)
{
  __shared__ __align__(16) u16 sXp[17408];  // 2 tiles * 64 rows * 136
  __shared__ __align__(16) u16 sH[9216];    // 4 waves * 2 tiles * 1152 (stride 72)

  int bid = blockIdx.x;          // 784 = 2b * 8t2 * 49s
  int b = bid / 392; int rem = bid - b*392;
  int t2 = rem / 49; int s2 = rem - t2*49;
  int hw0 = s2 * 64;
  int tid = threadIdx.x;
  int wv = tid >> 6, lane = tid & 63;
  int lrow = lane & 15, q = lane >> 4;
  const bool f32io = input_is_f32(xraw);

  // ---- phase A: ssm_out = elh@Wo + bo, LayerNorm -> sXp (tiles A: t2, B: t2+8) ----
  {
    int hw = hw0 + wv*16 + lrow;
    size_t tbA = ((size_t)(b*512) + t2)*3136;      // ((b*32+0)*16 + t2)*3136
    size_t tbB = tbA + (size_t)8*3136;
    union Cvt { uint4 u; bf16x8 v; };
    bf16x8 eA[4], eB[4];
#pragma unroll
    for (int kt = 0; kt < 4; ++kt){
      int cg0 = kt*8 + q*2;
      size_t eoA = (tbA + (size_t)cg0*50176 + hw)*4;
      size_t eoB = (tbB + (size_t)cg0*50176 + hw)*4;
      uint2 lo = *(const uint2*)(ELH + eoA);
      uint2 hi = *(const uint2*)(ELH + eoA + (size_t)50176*4);
      Cvt c1; c1.u = make_uint4(lo.x, lo.y, hi.x, hi.y); eA[kt] = c1.v;
      uint2 lo2 = *(const uint2*)(ELH + eoB);
      uint2 hi2 = *(const uint2*)(ELH + eoB + (size_t)50176*4);
      Cvt c2; c2.u = make_uint4(lo2.x, lo2.y, hi2.x, hi2.y); eB[kt] = c2.v;
    }

    float vA[8][4], vB[8][4];
#pragma unroll
    for (int nt = 0; nt < 8; ++nt){
      f32x4 aacc = {0.f,0.f,0.f,0.f}, bacc = {0.f,0.f,0.f,0.f};
      const u16* wr = WoT + (nt*16 + lrow)*128 + q*8;
#pragma unroll
      for (int kt = 0; kt < 4; ++kt){
        bf16x8 bfr = *(const bf16x8*)(wr + kt*32);
        aacc = MFMA16(eA[kt], bfr, aacc);
        bacc = MFMA16(eB[kt], bfr, bacc);
      }
      float bv = b2f(PRM[256 + nt*16 + lrow]);
#pragma unroll
      for (int i = 0; i < 4; ++i){ vA[nt][i] = aacc[i] + bv; vB[nt][i] = bacc[i] + bv; }
    }

#pragma unroll
    for (int i = 0; i < 4; ++i){
      float smA=0.f, sqA=0.f, smB=0.f, sqB=0.f;
#pragma unroll
      for (int nt = 0; nt < 8; ++nt){
        float a_ = vA[nt][i]; smA += a_; sqA = fmaf(a_, a_, sqA);
        float b_ = vB[nt][i]; smB += b_; sqB = fmaf(b_, b_, sqB);
      }
#pragma unroll
      for (int m = 1; m < 16; m <<= 1){
        smA += __shfl_xor(smA, m, 64); sqA += __shfl_xor(sqA, m, 64);
        smB += __shfl_xor(smB, m, 64); sqB += __shfl_xor(sqB, m, 64);
      }
      float mA = smA*(1.f/128.f), rA = rsqrtf(sqA*(1.f/128.f) - mA*mA + 1e-6f);
      float mB = smB*(1.f/128.f), rB = rsqrtf(sqB*(1.f/128.f) - mB*mB + 1e-6f);
      int r = wv*16 + q*4 + i;
#pragma unroll
      for (int nt = 0; nt < 8; ++nt){
        int c = nt*16 + lrow;
        float ls = b2f(PRM[384 + c]), lb = b2f(PRM[512 + c]);
        sXp[r*136 + c]        = f2b((vA[nt][i] - mA)*rA*ls + lb);
        sXp[8704 + r*136 + c] = f2b((vB[nt][i] - mB)*rB*ls + lb);
      }
    }
  }

  // a-frags: rows wv*16+lrow written by this same wave -> same-wave DS order, no barrier.
  bf16x8 aA[4], aB[4];
#pragma unroll
  for (int kt = 0; kt < 4; ++kt){
    aA[kt] = *(const bf16x8*)&sXp[(wv*16 + lrow)*136 + kt*32 + q*8];
    aB[kt] = *(const bf16x8*)&sXp[8704 + (wv*16 + lrow)*136 + kt*32 + q*8];
  }

  f32x4 accA[8], accB[8];
#pragma unroll
  for (int jo = 0; jo < 8; ++jo){ accA[jo] = (f32x4){0.f,0.f,0.f,0.f}; accB[jo] = (f32x4){0.f,0.f,0.f,0.f}; }
  u16* sHwA = sH + wv*2304;
  u16* sHwB = sHwA + 1152;

  // per-lane W bases; frag offsets: W1 (nt,js,kt) -> nt*8192 + js*2048 + kt*32 u16,
  //                                 W2 (jo,nt,kt2) -> jo*8192 + nt*64 + kt2*32 u16
  const u16* pW1 = W1T + lrow*128 + q*8;
  const u16* pW2 = W2T + (size_t)lrow*512 + q*8;

  for (int nt = 0; nt < 8; ++nt){
    const u16* w1n = pW1 + nt*8192;
    // ---- phase 1: H = gelu(XN @ W1tile + b1), both tiles share each W1 frag ----
#pragma unroll
    for (int js = 0; js < 4; ++js){
      f32x4 hcA = {0.f,0.f,0.f,0.f}, hcB = {0.f,0.f,0.f,0.f};
#pragma unroll
      for (int kt = 0; kt < 4; ++kt){
        bf16x8 f = *(const bf16x8*)(w1n + js*2048 + kt*32);
        hcA = MFMA16(aA[kt], f, hcA);
        hcB = MFMA16(aB[kt], f, hcB);
      }
      float bv = b2f(PRM[640 + nt*64 + js*16 + lrow]);
#pragma unroll
      for (int i = 0; i < 4; ++i){
        float vA_ = hcA[i] + bv;
        float uA = 0.79788456080286535588f*(vA_ + 0.044715f*vA_*vA_*vA_);
        float sA = __expf(-2.f*uA);
        sHwA[(q*4 + i)*72 + js*16 + lrow] =
            (u16)(__float_as_uint(vA_ * __builtin_amdgcn_rcpf(1.f + sA)) >> 16);
        float vB_ = hcB[i] + bv;
        float uB = 0.79788456080286535588f*(vB_ + 0.044715f*vB_*vB_*vB_);
        float sB = __expf(-2.f*uB);
        sHwB[(q*4 + i)*72 + js*16 + lrow] =
            (u16)(__float_as_uint(vB_ * __builtin_amdgcn_rcpf(1.f + sB)) >> 16);
      }
    }
    // ---- phase 2: acc += H @ W2tile, both tiles share each W2 frag ----
#pragma unroll
    for (int kt2 = 0; kt2 < 2; ++kt2){
      bf16x8 afA = *(const bf16x8*)&sHwA[lrow*72 + kt2*32 + q*8];
      bf16x8 afB = *(const bf16x8*)&sHwB[lrow*72 + kt2*32 + q*8];
      const u16* w2n = pW2 + nt*64 + kt2*32;
#pragma unroll
      for (int jo = 0; jo < 8; ++jo){
        bf16x8 f = *(const bf16x8*)(w2n + jo*8192);
        accA[jo] = MFMA16(afA, f, accA[jo]);
        accB[jo] = MFMA16(afB, f, accB[jo]);
      }
    }
  }

  // ---- epilogue: out = (acc + b2)*gamma + x  (both tiles) ----
  size_t rowA0 = ((size_t)(b*16 + t2))*3136 + hw0 + wv*16 + q*4;
  size_t rowB0 = rowA0 + (size_t)8*3136;
#pragma unroll
  for (int jo = 0; jo < 8; ++jo){
    int c = jo*16 + lrow;
    float bv  = b2f(PRM[1152 + c]);
    float gmv = b2f(PRM[1280 + c]);
#pragma unroll
    for (int i = 0; i < 4; ++i){
      size_t rA = rowA0 + i, rB = rowB0 + i;
      float yA = accA[jo][i] + bv, yB = accB[jo][i] + bv;
      if (f32io){
        float resA = ((const float*)xraw)[rA*128 + c];
        float resB = ((const float*)xraw)[rB*128 + c];
        ((float*)outv)[rA*128 + c] = yA*gmv + resA;
        ((float*)outv)[rB*128 + c] = yB*gmv + resB;
      } else {
        float resA = b2f(((const u16*)xraw)[rA*128 + c]);
        float resB = b2f(((const u16*)xraw)[rB*128 + c]);
        ((u16*)outv)[rA*128 + c] = f2b(yA*gmv + resA);
        ((u16*)outv)[rB*128 + c] = f2b(yB*gmv + resB);
      }
    }
  }
}

// ---------------- launch ----------------
extern "C" void kernel_launch(void* const* d_in, const int* in_sizes, int n_in,
                              void* d_out, int out_size, void* d_ws, size_t ws_size,
                              hipStream_t stream)
{
  const void* x   = d_in[0];
  const void* Wg  = d_in[1];
  const void* bg  = d_in[2];
  const void* Wh  = d_in[3];
  const void* bh  = d_in[4];
  const void* gk  = d_in[5];
  const void* hk  = d_in[6];
  const void* Wo  = d_in[7];
  const void* bo  = d_in[8];
  const void* lns = d_in[9];
  const void* lnb = d_in[10];
  const void* W1  = d_in[11];
  const void* b1  = d_in[12];
  const void* W2  = d_in[13];
  const void* b2  = d_in[14];
  const void* gm  = d_in[15];

  char* ws = (char*)d_ws;
  u16* GP  = (u16*)(ws + 0);              // 25,690,112 B each (f16)
  u16* HP  = (u16*)(ws + 25690112);
  u16* ELH = (u16*)(ws + 51380224);       // bf16
  u16* XB  = (u16*)(ws + 77070336);       // canonical bf16 x
  u16* WgT = (u16*)(ws + 102760448);
  u16* WhT = WgT + 16384;
  u16* WoT = WhT + 16384;
  u16* W1T = WoT + 16384;
  u16* W2T = W1T + 65536;
  unsigned* CIRG = (unsigned*)(W2T + 65536);   // 819,200 u32 = 3,276,800 B each
  unsigned* CIRH = CIRG + 819200;
  u16* PRM = (u16*)(CIRH + 819200);

  k0_prep        <<<dim3(512),  dim3(256), 0, stream>>>(x, Wg, Wh, Wo, W1, W2, gk, hk,
                                                        bg, bh, bo, lns, lnb, b1, b2, gm,
                                                        XB, WgT, WhT, WoT, W1T, W2T, CIRG, CIRH, PRM);
  k1_dualgemm    <<<dim3(1568), dim3(256), 0, stream>>>(XB, WgT, WhT, PRM, GP, HP);
  k2_conv_scan   <<<dim3(3136), dim3(256), 0, stream>>>(GP, HP, (const u16*)CIRG, (const u16*)CIRH, ELH);
  k34_gemm_ln_mlp<<<dim3(784),  dim3(256), 0, stream>>>(ELH, WoT, W1T, W2T, PRM, x, (void*)d_out);
}

// Round 8
// 399.614 us; speedup vs baseline: 1.1543x; 1.1543x over previous
//
#include <hip/hip_runtime.h>
#include <hip/hip_bf16.h>
#include <hip/hip_fp16.h>
#include <cstdint>
#include <cstddef>

typedef unsigned short u16;
typedef __attribute__((ext_vector_type(8))) short bf16x8;
typedef __attribute__((ext_vector_type(8))) _Float16 f16x8;
typedef __attribute__((ext_vector_type(4))) float f32x4;

#define MFMA16(a,b,c)  __builtin_amdgcn_mfma_f32_16x16x32_bf16((a),(b),(c),0,0,0)
#define MFMAF16(a,b,c) __builtin_amdgcn_mfma_f32_16x16x32_f16((a),(b),(c),0,0,0)

// B=2 T=16 H=W=56 C=128  HW=3136  N=100352  HID=512
// GP/HP (f16) layout: [b][cg32][hw3136][cl4][t16]  (t contiguous, 32B per (hw,cl))
//   u16 idx = (((b*32+cg)*3136 + hw)*4 + cl)*16 + t          slab = 200704 u16/(b,cg)
// ELH (bf16) layout: (((b*32+cg)*16 + t)*3136 + hw)*4 + cl
// CIRG/CIRH (f16 MFMA B-frags of temporal circulants, taps paired 2-per-MFMA):
//   u32 idx = ((c*25 + tp)*64 + lane)*4 + uu      (16B per lane per tap-pair)

static __device__ __forceinline__ float b2f(u16 u){ return __uint_as_float(((unsigned)u)<<16); }
static __device__ __forceinline__ u16 f2b(float f){
  unsigned u = __float_as_uint(f);
  return (u16)((u + 0x7fffu + ((u>>16)&1u)) >> 16);
}
static __device__ __forceinline__ u16 f2h(float f){ return __half_as_ushort(__float2half(f)); }

union U4F { uint4 u; f16x8 h; };

// async global->LDS 16B: LDS dest = wave-uniform base + lane*16, global src per-lane
static __device__ __forceinline__ void gld_lds16(const void* g, void* l){
  __builtin_amdgcn_global_load_lds(
      (const __attribute__((address_space(1))) void*)g,
      (__attribute__((address_space(3))) void*)l, 16, 0, 0);
}

// dtype detector: sample 64 even-index u16 words of x. bf16 N(0,1) data -> exponent
// field in [100,140] essentially always; f32 -> mantissa halves, ~uniform exponent.
static __device__ __forceinline__ bool input_is_f32(const void* xp){
  const u16* u = (const u16*)xp;
  int cnt = 0;
#pragma unroll
  for (int i = 0; i < 64; ++i){
    unsigned e = (u[2*i] >> 7) & 0xFF;
    cnt += (e >= 100 && e <= 140) ? 1 : 0;
  }
  return cnt < 32;
}

static __device__ __forceinline__ u16 ldb(const void* p, int i, bool f32){
  return f32 ? f2b(((const float*)p)[i]) : ((const u16*)p)[i];
}
static __device__ __forceinline__ float ldf(const void* p, int i, bool f32){
  return f32 ? ((const float*)p)[i] : b2f(((const u16*)p)[i]);
}

// ---------------- K0: canonicalize inputs (+ transposes + circulant B-frag build) ----------------
__global__ __launch_bounds__(256) void k0_prep(
    const void* __restrict__ x,
    const void* __restrict__ Wg, const void* __restrict__ Wh, const void* __restrict__ Wo,
    const void* __restrict__ W1, const void* __restrict__ W2,
    const void* __restrict__ gk, const void* __restrict__ hk,
    const void* __restrict__ bg, const void* __restrict__ bh, const void* __restrict__ bo,
    const void* __restrict__ lns, const void* __restrict__ lnb,
    const void* __restrict__ b1, const void* __restrict__ b2, const void* __restrict__ gm,
    u16* __restrict__ XB,
    u16* __restrict__ WgT, u16* __restrict__ WhT, u16* __restrict__ WoT,
    u16* __restrict__ W1T, u16* __restrict__ W2T,
    unsigned* __restrict__ CIRG, unsigned* __restrict__ CIRH, u16* __restrict__ PRM)
{
  const bool f32 = input_is_f32(x);
  int tid = blockIdx.x*blockDim.x + threadIdx.x;
  int np  = gridDim.x*blockDim.x;

  // x -> XB (bf16), 2 elements per u32 store
  if (f32){
    const float* xf = (const float*)x;
    for (int p = tid; p < 6422528; p += np){
      unsigned v = (unsigned)f2b(xf[2*p]) | ((unsigned)f2b(xf[2*p+1]) << 16);
      ((unsigned*)XB)[p] = v;
    }
  } else {
    const unsigned* xu = (const unsigned*)x;
    for (int p = tid; p < 6422528; p += np) ((unsigned*)XB)[p] = xu[p];
  }

  for (int p = tid; p < 16384; p += np){           // 128x128 transposes
    int n = p>>7, k = p&127;
    WgT[p] = ldb(Wg, k*128+n, f32);
    WhT[p] = ldb(Wh, k*128+n, f32);
    WoT[p] = ldb(Wo, k*128+n, f32);
  }
  for (int p = tid; p < 65536; p += np){           // W1 (128,512) -> W1T (512,128)
    int n = p>>7, k = p&127;
    W1T[p] = ldb(W1, k*512+n, f32);
  }
  for (int p = tid; p < 65536; p += np){           // W2 (512,128) -> W2T (128,512)
    int n = p>>9, k = p&511;
    W2T[p] = ldb(W2, k*128+n, f32);
  }

  // circulant B-fragments for mfma_f32_16x16x32_f16:
  //   B[k][n]: n = t_out (lane&15), k = (lane>>4)*8 + jj; tap-pair tp: spatial tap
  //   tapA = 2tp (k<16), tapB = 2tp+1 (k>=16, zero-padded at tp=24).
  //   B[k][n] = w[c][tap][(n - t_in + 2) mod 16] if that temporal idx < 5 else 0,
  //   with t_in = (k&15). gate/hidden kernel layout (C,5,7,7): w = gk[c*245 + i*49 + tap]
  for (int p = tid; p < 819200; p += np){
    int uu = p & 3;
    int lane = (p >> 2) & 63;
    int tpc = p >> 8;                 // c*25 + tp
    int c = tpc / 25, tp = tpc - c*25;
    int qq = lane >> 4, nn = lane & 15;
    int tap = 2*tp + (qq >> 1);
    unsigned vg = 0, vh = 0;
    if (tap < 49){
      int kk = ((qq & 1) << 3) + uu*2;          // t_in of low f16
      int i0 = (nn - kk + 2) & 15;
      int i1 = (nn - kk + 1) & 15;              // t_in + 1
      unsigned g0 = (i0 < 5) ? (unsigned)f2h(ldf(gk, c*245 + i0*49 + tap, f32)) : 0u;
      unsigned h0 = (i0 < 5) ? (unsigned)f2h(ldf(hk, c*245 + i0*49 + tap, f32)) : 0u;
      unsigned g1 = (i1 < 5) ? (unsigned)f2h(ldf(gk, c*245 + i1*49 + tap, f32)) : 0u;
      unsigned h1 = (i1 < 5) ? (unsigned)f2h(ldf(hk, c*245 + i1*49 + tap, f32)) : 0u;
      vg = g0 | (g1 << 16);
      vh = h0 | (h1 << 16);
    }
    CIRG[p] = vg; CIRH[p] = vh;
  }

  // param block (bf16): bg@0 bh@128 bo@256 lns@384 lnb@512 b1@640 b2@1152 gamma@1280
  for (int p = tid; p < 1408; p += np){
    const void* src; int off;
    if      (p < 128)  { src = bg;  off = p; }
    else if (p < 256)  { src = bh;  off = p-128; }
    else if (p < 384)  { src = bo;  off = p-256; }
    else if (p < 512)  { src = lns; off = p-384; }
    else if (p < 640)  { src = lnb; off = p-512; }
    else if (p < 1152) { src = b1;  off = p-640; }
    else if (p < 1280) { src = b2;  off = p-1152; }
    else               { src = gm;  off = p-1280; }
    PRM[p] = ldb(src, off, f32);
  }
}

// ---------------- K1: dual GEMM  gate = x@Wg+bg, hidden = x@Wh+bh (f16 out, t-contiguous) ----------------
__global__ __launch_bounds__(256) void k1_dualgemm(
    const u16* __restrict__ XB, const u16* __restrict__ WgT, const u16* __restrict__ WhT,
    const u16* __restrict__ PRM,
    u16* __restrict__ GP, u16* __restrict__ HP)
{
  int bid = blockIdx.x;                  // 1568 = 2b * 784 hw-groups
  int b = bid / 784; int hw = (bid % 784)*4 + (threadIdx.x >> 6);
  int lane = threadIdx.x & 63;
  int lrow = lane & 15, q = lane >> 4;

  bf16x8 a[4];   // A row (in-tile) = lrow = t; k-cols q*8 + kt*32
  const u16* xr = XB + ((size_t)(b*16 + lrow)*3136 + hw)*128 + q*8;
#pragma unroll
  for (int kt = 0; kt < 4; ++kt) a[kt] = *(const bf16x8*)(xr + kt*32);

#pragma unroll
  for (int mat = 0; mat < 2; ++mat){
    const u16* WT  = mat ? WhT : WgT;
    const u16* bia = PRM + (mat ? 128 : 0);
    u16* out       = mat ? HP  : GP;
#pragma unroll
    for (int nt = 0; nt < 8; ++nt){
      f32x4 acc = {0.f,0.f,0.f,0.f};
      const u16* wr = WT + (nt*16 + lrow)*128 + q*8;
#pragma unroll
      for (int kt = 0; kt < 4; ++kt){
        bf16x8 bfr = *(const bf16x8*)(wr + kt*32);
        acc = MFMA16(a[kt], bfr, acc);
      }
      int c = nt*16 + lrow;              // C col = output channel
      float bv = b2f(bia[c]);
      size_t base = (((size_t)(b*32 + (c>>2))*3136 + hw)*4 + (c&3))*16 + q*4;
      ushort4 pk;
      pk.x = f2h(acc[0] + bv); pk.y = f2h(acc[1] + bv);
      pk.z = f2h(acc[2] + bv); pk.w = f2h(acc[3] + bv);
      *(ushort4*)(out + base) = pk;      // t = q*4 .. q*4+3
    }
  }
}

// ---------------- K2: circular 5x7x7 depthwise conv via MFMA circulants + linear scan ----------------
__global__ __launch_bounds__(256, 5) void k2_conv_scan(
    const u16* __restrict__ GP, const u16* __restrict__ HP,
    const u16* __restrict__ CIRG, const u16* __restrict__ CIRH,
    u16* __restrict__ ELH)
{
  __shared__ __align__(16) unsigned su[6272];   // 25,088 B

  int bid = blockIdx.x;                    // 3136 = 2 * 32 * 49
  int b = bid / 1568; int rr = bid - b*1568;
  int cg = rr / 49; int s = rr % 49;
  int th = s / 7, tw = s % 7;
  int tid = threadIdx.x;
  int h0g = th*8, w0g = tw*8;
  size_t tb = (size_t)(b*32 + cg)*200704;  // u16 slab base (GP/HP/ELH identical value)

  int wv = tid >> 6, lane = tid & 63;
  int q = lane >> 4, lrow = lane & 15;
  int hb = lrow >> 3, wb = lrow & 7;       // spatial of A-row at m=0: h=hb, w=wb

  int cu = __builtin_amdgcn_readfirstlane(cg*4 + wv);
  const u16* cirg = CIRG + (size_t)cu*12800;   // 25 tp * 64 lane * 8 u16
  const u16* cirh = CIRH + (size_t)cu*12800;

  // ---- staging chunk offsets: chunk ci = cl*392 + pos*2 + half  (LDS addr = ci*16, linear) ----
  unsigned soff[7]; bool sval[7];
#pragma unroll
  for (int ss = 0; ss < 7; ++ss){
    int ci = ss*256 + tid;
    sval[ss] = (ci < 1568);
    int clc = ci / 392;
    int rem = ci - clc*392;
    int pos = rem >> 1, half = rem & 1;
    int hh = pos / 14, ww = pos - hh*14;
    int hg = h0g + hh - 3; if (hg < 0) hg += 56; else if (hg >= 56) hg -= 56;
    int wg = w0g + ww - 3; if (wg < 0) wg += 56; else if (wg >= 56) wg -= 56;
    soff[ss] = (unsigned)((hg*56 + wg)*128 + clc*32 + half*16);
  }
  const char* gpb = (const char*)(GP + tb);
  const char* hpb = (const char*)(HP + tb);

  auto stagepass = [&](const char* Pb){
#pragma unroll
    for (int ss = 0; ss < 7; ++ss){
      if (sval[ss])
        gld_lds16(Pb + soff[ss], (char*)su + (ss*256 + wv*64)*16);
    }
  };

  auto convpass = [&](const u16* cir, f32x4* acc){
#pragma unroll
    for (int m = 0; m < 4; ++m) acc[m] = (f32x4){0.f,0.f,0.f,0.f};
    U4F bq0, bq1, bq2;
    bq0.u = *(const uint4*)(cir + 0*512 + lane*8);
    bq1.u = *(const uint4*)(cir + 1*512 + lane*8);
    bq2.u = *(const uint4*)(cir + 2*512 + lane*8);
    const int base_cl = wv*6272;
#pragma unroll
    for (int tp = 0; tp < 25; ++tp){
      const int tA = 2*tp;
      const int tB = (2*tp + 1 > 48) ? 48 : 2*tp + 1;
      const int dhA = 6 - tA/7, dwA = 6 - tA%7;
      const int dhB = 6 - tB/7, dwB = 6 - tB%7;
      int dh = (q >= 2) ? dhB : dhA;
      int dw = (q >= 2) ? dwB : dwA;
      const char* sp = (const char*)su +
          (base_cl + ((hb + dh)*14 + (wb + dw))*32 + (q & 1)*16);
      U4F a0, a1, a2, a3;
      a0.u = *(const uint4*)(sp);
      a1.u = *(const uint4*)(sp + 896);    // m=1: h += 2 -> pos += 28
      a2.u = *(const uint4*)(sp + 1792);
      a3.u = *(const uint4*)(sp + 2688);
      f16x8 bb = (tp % 3 == 0) ? bq0.h : (tp % 3 == 1) ? bq1.h : bq2.h;
      acc[0] = MFMAF16(a0.h, bb, acc[0]);
      acc[1] = MFMAF16(a1.h, bb, acc[1]);
      acc[2] = MFMAF16(a2.h, bb, acc[2]);
      acc[3] = MFMAF16(a3.h, bb, acc[3]);
      if (tp + 3 < 25){
        uint4 nb = *(const uint4*)(cir + (tp+3)*512 + lane*8);
        if (tp % 3 == 0) bq0.u = nb; else if (tp % 3 == 1) bq1.u = nb; else bq2.u = nb;
      }
    }
  };

  f32x4 accG[4], accH[4];
  stagepass(gpb);
  __syncthreads();          // gld_lds data resident
  convpass(cirg, accG);
  __syncthreads();          // conv reads done before restage overwrites
  stagepass(hpb);
  __syncthreads();
  convpass(cirh, accH);

  // ---- pointwise (linear-space) ----
  float fv[16], vv[16];
#pragma unroll
  for (int e = 0; e < 16; ++e){
    float g  = accG[e>>2][e&3];
    float hc = accH[e>>2][e&3];
    float eg = __expf(g);
    float fr = __builtin_amdgcn_rcpf(1.f + eg);   // 1 - z = sigmoid(-g)
    float zz = 1.f - fr;                          // z = sigmoid(g), inf-safe
    fv[e] = fr;
    vv[e] = (hc*hc + 1e-6f) * zz;
  }
  // ---- inclusive scan over t (= lrow) within 16-lane groups ----
#pragma unroll
  for (int d = 1; d < 16; d <<= 1){
    bool ok = (lrow >= d);
#pragma unroll
    for (int e = 0; e < 16; ++e){
      float Lf = __shfl_up(fv[e], (unsigned)d, 16);
      float Lv = __shfl_up(vv[e], (unsigned)d, 16);
      Lf = ok ? Lf : 1.f;
      Lv = ok ? Lv : 0.f;
      vv[e] = fmaf(fv[e], Lv, vv[e]);
      fv[e] = fv[e] * Lf;
    }
  }
  // ---- store h = vv (bf16) ----
  size_t ob = tb + (size_t)lrow*12544 + (size_t)(h0g*56 + w0g)*4 + wv;
#pragma unroll
  for (int e = 0; e < 16; ++e){
    int r = (e>>2)*16 + q*4 + (e&3);
    ELH[ob + (size_t)((r>>3)*56 + (r&7))*4] = f2b(vv[e]);
  }
}

// ---------------- K34 v6: R5's v3 structure + shared W-frags across tiles + swizzled sH ----------------
// Known-good v3 schedule (gld_lds dbuf staging, vmcnt(0)+s_barrier per nt). One change:
// each W fragment is loaded from LDS ONCE and fed to both tiles' MFMAs (was 2x reads),
// which requires both H scratches live -> sH = 8 KB/wave pair, stride-64 XOR swizzle (R6-verified).
// LDS total: 65,536 (sW dbuf, sXp aliases) + 16,384 (sH) = 81,920 B -> 2 blocks/CU.
__global__ __launch_bounds__(256, 2) void k34_gemm_ln_mlp(
    const u16* __restrict__ ELH, const u16* __restrict__ WoT,
    const u16* __restrict__ W1T, const u16* __restrict__ W2T,
    const u16* __restrict__ PRM,
    const void* __restrict__ xraw, void* __restrict__ outv)
{
  __shared__ __align__(16) u16 smem[40960];   // 81,920 B
  u16* sW0 = smem;               // 16384 u16 (32 KB)
  u16* sW1 = smem + 16384;       // 16384 u16
  u16* sXp = smem;               // 2*64*136 = 17408 u16 (phase A only; dead before staging)
  u16* sH  = smem + 32768;       // 4 waves * 2 tiles * 1024 u16 (stride 64 + XOR swizzle)

  int bid = blockIdx.x;          // 784 = 2b * 8t2 * 49s
  int b = bid / 392; int rem = bid - b*392;
  int t2 = rem / 49; int s2 = rem - t2*49;
  int hw0 = s2 * 64;
  int tid = threadIdx.x;
  int wv = tid >> 6, lane = tid & 63;
  int lrow = lane & 15, q = lane >> 4;
  const bool f32io = input_is_f32(xraw);

  // ---- phase A: ssm_out = elh@Wo + bo, LayerNorm -> sXp (tiles A: t2, B: t2+8) ----
  {
    int hw = hw0 + wv*16 + lrow;
    size_t tbA = ((size_t)(b*512) + t2)*3136;      // ((b*32+0)*16 + t2)*3136
    size_t tbB = tbA + (size_t)8*3136;
    union Cvt { uint4 u; bf16x8 v; };
    bf16x8 eA[4], eB[4];
#pragma unroll
    for (int kt = 0; kt < 4; ++kt){
      int cg0 = kt*8 + q*2;
      size_t eoA = (tbA + (size_t)cg0*50176 + hw)*4;
      size_t eoB = (tbB + (size_t)cg0*50176 + hw)*4;
      uint2 lo = *(const uint2*)(ELH + eoA);
      uint2 hi = *(const uint2*)(ELH + eoA + (size_t)50176*4);
      Cvt c1; c1.u = make_uint4(lo.x, lo.y, hi.x, hi.y); eA[kt] = c1.v;
      uint2 lo2 = *(const uint2*)(ELH + eoB);
      uint2 hi2 = *(const uint2*)(ELH + eoB + (size_t)50176*4);
      Cvt c2; c2.u = make_uint4(lo2.x, lo2.y, hi2.x, hi2.y); eB[kt] = c2.v;
    }

    float vA[8][4], vB[8][4];
#pragma unroll
    for (int nt = 0; nt < 8; ++nt){
      f32x4 aacc = {0.f,0.f,0.f,0.f}, bacc = {0.f,0.f,0.f,0.f};
      const u16* wr = WoT + (nt*16 + lrow)*128 + q*8;
#pragma unroll
      for (int kt = 0; kt < 4; ++kt){
        bf16x8 bfr = *(const bf16x8*)(wr + kt*32);
        aacc = MFMA16(eA[kt], bfr, aacc);
        bacc = MFMA16(eB[kt], bfr, bacc);
      }
      float bv = b2f(PRM[256 + nt*16 + lrow]);
#pragma unroll
      for (int i = 0; i < 4; ++i){ vA[nt][i] = aacc[i] + bv; vB[nt][i] = bacc[i] + bv; }
    }

#pragma unroll
    for (int i = 0; i < 4; ++i){
      float smA=0.f, sqA=0.f, smB=0.f, sqB=0.f;
#pragma unroll
      for (int nt = 0; nt < 8; ++nt){
        float a_ = vA[nt][i]; smA += a_; sqA = fmaf(a_, a_, sqA);
        float b_ = vB[nt][i]; smB += b_; sqB = fmaf(b_, b_, sqB);
      }
#pragma unroll
      for (int m = 1; m < 16; m <<= 1){
        smA += __shfl_xor(smA, m, 64); sqA += __shfl_xor(sqA, m, 64);
        smB += __shfl_xor(smB, m, 64); sqB += __shfl_xor(sqB, m, 64);
      }
      float mA = smA*(1.f/128.f), rA = rsqrtf(sqA*(1.f/128.f) - mA*mA + 1e-6f);
      float mB = smB*(1.f/128.f), rB = rsqrtf(sqB*(1.f/128.f) - mB*mB + 1e-6f);
      int r = wv*16 + q*4 + i;
#pragma unroll
      for (int nt = 0; nt < 8; ++nt){
        int c = nt*16 + lrow;
        float ls = b2f(PRM[384 + c]), lb = b2f(PRM[512 + c]);
        sXp[r*136 + c]        = f2b((vA[nt][i] - mA)*rA*ls + lb);
        sXp[8704 + r*136 + c] = f2b((vB[nt][i] - mB)*rB*ls + lb);
      }
    }
  }

  // a-frags: rows written by this same wave -> readable without barrier
  bf16x8 aA[4], aB[4];
#pragma unroll
  for (int kt = 0; kt < 4; ++kt){
    aA[kt] = *(const bf16x8*)&sXp[(wv*16 + lrow)*136 + kt*32 + q*8];
    aB[kt] = *(const bf16x8*)&sXp[8704 + (wv*16 + lrow)*136 + kt*32 + q*8];
  }
  __syncthreads();   // all waves done with sXp before W staging overwrites it

  // per-thread W-tile global srcs (nt advance: W1 part +8192, W2 part +64)
  const u16* wsrc[8];
#pragma unroll
  for (int r = 0; r < 8; ++r){
    int c = r*4 + wv;
    if (c < 16){
      int j = c >> 2, kt = c & 3;
      wsrc[r] = W1T + (size_t)(j*16 + lrow)*128 + kt*32 + q*8;
    } else {
      int c2 = c - 16; int jo = c2 >> 1, kt2 = c2 & 1;
      wsrc[r] = W2T + (size_t)(jo*16 + lrow)*512 + kt2*32 + q*8;
    }
  }
  auto stage = [&](u16* buf, int nt){
#pragma unroll
    for (int r = 0; r < 8; ++r){
      int c = r*4 + wv;
      const u16* src = wsrc[r] + (c < 16 ? (size_t)nt*8192 : (size_t)nt*64);
      gld_lds16(src, buf + c*512);            // dest wave-uniform; HW adds lane*16B
    }
  };

  f32x4 accA[8], accB[8];
#pragma unroll
  for (int jo = 0; jo < 8; ++jo){ accA[jo] = (f32x4){0.f,0.f,0.f,0.f}; accB[jo] = (f32x4){0.f,0.f,0.f,0.f}; }
  u16* sHwA = sH + wv*2048;
  u16* sHwB = sHwA + 1024;

  stage(sW0, 0);
  asm volatile("s_waitcnt vmcnt(0)" ::: "memory");
  __builtin_amdgcn_s_barrier();

  auto mlpstep = [&](int nt, u16* wcur, u16* wnxt, bool do_stage){
    if (do_stage) stage(wnxt, nt+1);          // in flight under compute
    // ---- phase 1: H = gelu(XN @ W1tile + b1); each W1 frag read ONCE, used by A and B ----
#pragma unroll
    for (int js = 0; js < 4; ++js){
      f32x4 hcA = {0.f,0.f,0.f,0.f}, hcB = {0.f,0.f,0.f,0.f};
#pragma unroll
      for (int kt = 0; kt < 4; ++kt){
        bf16x8 f = *(const bf16x8*)&wcur[(js*4 + kt)*512 + lane*8];
        hcA = MFMA16(aA[kt], f, hcA);
        hcB = MFMA16(aB[kt], f, hcB);
      }
      float bv = b2f(PRM[640 + nt*64 + js*16 + lrow]);
#pragma unroll
      for (int i = 0; i < 4; ++i){
        int r = q*4 + i;
        int cidx = (js*16 + lrow) ^ ((r & 7) << 3);   // 8-u16 granule XOR swizzle
        float vA_ = hcA[i] + bv;
        float uA = 0.79788456080286535588f*(vA_ + 0.044715f*vA_*vA_*vA_);
        float sA = __expf(-2.f*uA);
        sHwA[r*64 + cidx] = (u16)(__float_as_uint(vA_ * __builtin_amdgcn_rcpf(1.f + sA)) >> 16);
        float vB_ = hcB[i] + bv;
        float uB = 0.79788456080286535588f*(vB_ + 0.044715f*vB_*vB_*vB_);
        float sB = __expf(-2.f*uB);
        sHwB[r*64 + cidx] = (u16)(__float_as_uint(vB_ * __builtin_amdgcn_rcpf(1.f + sB)) >> 16);
      }
    }
    // ---- phase 2: acc += H @ W2tile; each W2 frag read ONCE, used by A and B ----
#pragma unroll
    for (int kt2 = 0; kt2 < 2; ++kt2){
      int hoff = (kt2*32 + q*8) ^ ((lrow & 7) << 3);
      bf16x8 afA = *(const bf16x8*)&sHwA[lrow*64 + hoff];
      bf16x8 afB = *(const bf16x8*)&sHwB[lrow*64 + hoff];
#pragma unroll
      for (int jo = 0; jo < 8; ++jo){
        bf16x8 f = *(const bf16x8*)&wcur[(16 + jo*2 + kt2)*512 + lane*8];
        accA[jo] = MFMA16(afA, f, accA[jo]);
        accB[jo] = MFMA16(afB, f, accB[jo]);
      }
    }
    asm volatile("s_waitcnt vmcnt(0)" ::: "memory");   // staged tile landed
    __builtin_amdgcn_s_barrier();
  };

  for (int nt2 = 0; nt2 < 4; ++nt2){
    mlpstep(2*nt2,     sW0, sW1, true);
    mlpstep(2*nt2 + 1, sW1, sW0, nt2 < 3);
  }

  // ---- epilogue: out = (acc + b2)*gamma + x  (both tiles) ----
  size_t rowA0 = ((size_t)(b*16 + t2))*3136 + hw0 + wv*16 + q*4;
  size_t rowB0 = rowA0 + (size_t)8*3136;
#pragma unroll
  for (int jo = 0; jo < 8; ++jo){
    int c = jo*16 + lrow;
    float bv  = b2f(PRM[1152 + c]);
    float gmv = b2f(PRM[1280 + c]);
#pragma unroll
    for (int i = 0; i < 4; ++i){
      size_t rA = rowA0 + i, rB = rowB0 + i;
      float yA = accA[jo][i] + bv, yB = accB[jo][i] + bv;
      if (f32io){
        float resA = ((const float*)xraw)[rA*128 + c];
        float resB = ((const float*)xraw)[rB*128 + c];
        ((float*)outv)[rA*128 + c] = yA*gmv + resA;
        ((float*)outv)[rB*128 + c] = yB*gmv + resB;
      } else {
        float resA = b2f(((const u16*)xraw)[rA*128 + c]);
        float resB = b2f(((const u16*)xraw)[rB*128 + c]);
        ((u16*)outv)[rA*128 + c] = f2b(yA*gmv + resA);
        ((u16*)outv)[rB*128 + c] = f2b(yB*gmv + resB);
      }
    }
  }
}

// ---------------- launch ----------------
extern "C" void kernel_launch(void* const* d_in, const int* in_sizes, int n_in,
                              void* d_out, int out_size, void* d_ws, size_t ws_size,
                              hipStream_t stream)
{
  const void* x   = d_in[0];
  const void* Wg  = d_in[1];
  const void* bg  = d_in[2];
  const void* Wh  = d_in[3];
  const void* bh  = d_in[4];
  const void* gk  = d_in[5];
  const void* hk  = d_in[6];
  const void* Wo  = d_in[7];
  const void* bo  = d_in[8];
  const void* lns = d_in[9];
  const void* lnb = d_in[10];
  const void* W1  = d_in[11];
  const void* b1  = d_in[12];
  const void* W2  = d_in[13];
  const void* b2  = d_in[14];
  const void* gm  = d_in[15];

  char* ws = (char*)d_ws;
  u16* GP  = (u16*)(ws + 0);              // 25,690,112 B each (f16)
  u16* HP  = (u16*)(ws + 25690112);
  u16* ELH = (u16*)(ws + 51380224);       // bf16
  u16* XB  = (u16*)(ws + 77070336);       // canonical bf16 x
  u16* WgT = (u16*)(ws + 102760448);
  u16* WhT = WgT + 16384;
  u16* WoT = WhT + 16384;
  u16* W1T = WoT + 16384;
  u16* W2T = W1T + 65536;
  unsigned* CIRG = (unsigned*)(W2T + 65536);   // 819,200 u32 = 3,276,800 B each
  unsigned* CIRH = CIRG + 819200;
  u16* PRM = (u16*)(CIRH + 819200);

  k0_prep        <<<dim3(512),  dim3(256), 0, stream>>>(x, Wg, Wh, Wo, W1, W2, gk, hk,
                                                        bg, bh, bo, lns, lnb, b1, b2, gm,
                                                        XB, WgT, WhT, WoT, W1T, W2T, CIRG, CIRH, PRM);
  k1_dualgemm    <<<dim3(1568), dim3(256), 0, stream>>>(XB, WgT, WhT, PRM, GP, HP);
  k2_conv_scan   <<<dim3(3136), dim3(256), 0, stream>>>(GP, HP, (const u16*)CIRG, (const u16*)CIRH, ELH);
  k34_gemm_ln_mlp<<<dim3(784),  dim3(256), 0, stream>>>(ELH, WoT, W1T, W2T, PRM, x, (void*)d_out);
}

// Round 9
// 397.879 us; speedup vs baseline: 1.1593x; 1.0044x over previous
//
#include <hip/hip_runtime.h>
#include <hip/hip_bf16.h>
#include <hip/hip_fp16.h>
#include <cstdint>
#include <cstddef>

typedef unsigned short u16;
typedef __attribute__((ext_vector_type(8))) short bf16x8;
typedef __attribute__((ext_vector_type(8))) _Float16 f16x8;
typedef __attribute__((ext_vector_type(4))) float f32x4;

#define MFMA16(a,b,c)  __builtin_amdgcn_mfma_f32_16x16x32_bf16((a),(b),(c),0,0,0)
#define MFMAF16(a,b,c) __builtin_amdgcn_mfma_f32_16x16x32_f16((a),(b),(c),0,0,0)

// B=2 T=16 H=W=56 C=128  HW=3136  N=100352  HID=512
// GP/HP (f16) layout: [b][hw3136][c128][t16]  (t contiguous; (hw, 4-channel group) = 128B region)
//   u16 idx = ((b*3136 + hw)*128 + c)*16 + t          slab = 6,422,528 u16 per b
// ELH (bf16) layout: (((b*32+cg)*16 + t)*3136 + hw)*4 + cl
// CIRG/CIRH (f16 MFMA B-frags of temporal circulants, taps paired 2-per-MFMA):
//   u32 idx = ((c*25 + tp)*64 + lane)*4 + uu      (16B per lane per tap-pair)

static __device__ __forceinline__ float b2f(u16 u){ return __uint_as_float(((unsigned)u)<<16); }
static __device__ __forceinline__ u16 f2b(float f){
  unsigned u = __float_as_uint(f);
  return (u16)((u + 0x7fffu + ((u>>16)&1u)) >> 16);
}
static __device__ __forceinline__ u16 f2h(float f){ return __half_as_ushort(__float2half(f)); }

union U4F { uint4 u; f16x8 h; };

// async global->LDS 16B: LDS dest = wave-uniform base + lane*16, global src per-lane
static __device__ __forceinline__ void gld_lds16(const void* g, void* l){
  __builtin_amdgcn_global_load_lds(
      (const __attribute__((address_space(1))) void*)g,
      (__attribute__((address_space(3))) void*)l, 16, 0, 0);
}

// dtype detector: sample 64 even-index u16 words of x. bf16 N(0,1) data -> exponent
// field in [100,140] essentially always; f32 -> mantissa halves, ~uniform exponent.
static __device__ __forceinline__ bool input_is_f32(const void* xp){
  const u16* u = (const u16*)xp;
  int cnt = 0;
#pragma unroll
  for (int i = 0; i < 64; ++i){
    unsigned e = (u[2*i] >> 7) & 0xFF;
    cnt += (e >= 100 && e <= 140) ? 1 : 0;
  }
  return cnt < 32;
}

static __device__ __forceinline__ u16 ldb(const void* p, int i, bool f32){
  return f32 ? f2b(((const float*)p)[i]) : ((const u16*)p)[i];
}
static __device__ __forceinline__ float ldf(const void* p, int i, bool f32){
  return f32 ? ((const float*)p)[i] : b2f(((const u16*)p)[i]);
}

// ---------------- K0: canonicalize inputs (+ transposes + circulant B-frag build) ----------------
__global__ __launch_bounds__(256) void k0_prep(
    const void* __restrict__ x,
    const void* __restrict__ Wg, const void* __restrict__ Wh, const void* __restrict__ Wo,
    const void* __restrict__ W1, const void* __restrict__ W2,
    const void* __restrict__ gk, const void* __restrict__ hk,
    const void* __restrict__ bg, const void* __restrict__ bh, const void* __restrict__ bo,
    const void* __restrict__ lns, const void* __restrict__ lnb,
    const void* __restrict__ b1, const void* __restrict__ b2, const void* __restrict__ gm,
    u16* __restrict__ XB,
    u16* __restrict__ WgT, u16* __restrict__ WhT, u16* __restrict__ WoT,
    u16* __restrict__ W1T, u16* __restrict__ W2T,
    unsigned* __restrict__ CIRG, unsigned* __restrict__ CIRH, u16* __restrict__ PRM)
{
  const bool f32 = input_is_f32(x);
  int tid = blockIdx.x*blockDim.x + threadIdx.x;
  int np  = gridDim.x*blockDim.x;

  // x -> XB (bf16), 2 elements per u32 store
  if (f32){
    const float* xf = (const float*)x;
    for (int p = tid; p < 6422528; p += np){
      unsigned v = (unsigned)f2b(xf[2*p]) | ((unsigned)f2b(xf[2*p+1]) << 16);
      ((unsigned*)XB)[p] = v;
    }
  } else {
    const unsigned* xu = (const unsigned*)x;
    for (int p = tid; p < 6422528; p += np) ((unsigned*)XB)[p] = xu[p];
  }

  for (int p = tid; p < 16384; p += np){           // 128x128 transposes
    int n = p>>7, k = p&127;
    WgT[p] = ldb(Wg, k*128+n, f32);
    WhT[p] = ldb(Wh, k*128+n, f32);
    WoT[p] = ldb(Wo, k*128+n, f32);
  }
  for (int p = tid; p < 65536; p += np){           // W1 (128,512) -> W1T (512,128)
    int n = p>>7, k = p&127;
    W1T[p] = ldb(W1, k*512+n, f32);
  }
  for (int p = tid; p < 65536; p += np){           // W2 (512,128) -> W2T (128,512)
    int n = p>>9, k = p&511;
    W2T[p] = ldb(W2, k*128+n, f32);
  }

  // circulant B-fragments for mfma_f32_16x16x32_f16:
  //   B[k][n]: n = t_out (lane&15), k = (lane>>4)*8 + jj; tap-pair tp: spatial tap
  //   tapA = 2tp (k<16), tapB = 2tp+1 (k>=16, zero-padded at tp=24).
  //   B[k][n] = w[c][tap][(n - t_in + 2) mod 16] if that temporal idx < 5 else 0,
  //   with t_in = (k&15). gate/hidden kernel layout (C,5,7,7): w = gk[c*245 + i*49 + tap]
  for (int p = tid; p < 819200; p += np){
    int uu = p & 3;
    int lane = (p >> 2) & 63;
    int tpc = p >> 8;                 // c*25 + tp
    int c = tpc / 25, tp = tpc - c*25;
    int qq = lane >> 4, nn = lane & 15;
    int tap = 2*tp + (qq >> 1);
    unsigned vg = 0, vh = 0;
    if (tap < 49){
      int kk = ((qq & 1) << 3) + uu*2;          // t_in of low f16
      int i0 = (nn - kk + 2) & 15;
      int i1 = (nn - kk + 1) & 15;              // t_in + 1
      unsigned g0 = (i0 < 5) ? (unsigned)f2h(ldf(gk, c*245 + i0*49 + tap, f32)) : 0u;
      unsigned h0 = (i0 < 5) ? (unsigned)f2h(ldf(hk, c*245 + i0*49 + tap, f32)) : 0u;
      unsigned g1 = (i1 < 5) ? (unsigned)f2h(ldf(gk, c*245 + i1*49 + tap, f32)) : 0u;
      unsigned h1 = (i1 < 5) ? (unsigned)f2h(ldf(hk, c*245 + i1*49 + tap, f32)) : 0u;
      vg = g0 | (g1 << 16);
      vh = h0 | (h1 << 16);
    }
    CIRG[p] = vg; CIRH[p] = vh;
  }

  // param block (bf16): bg@0 bh@128 bo@256 lns@384 lnb@512 b1@640 b2@1152 gamma@1280
  for (int p = tid; p < 1408; p += np){
    const void* src; int off;
    if      (p < 128)  { src = bg;  off = p; }
    else if (p < 256)  { src = bh;  off = p-128; }
    else if (p < 384)  { src = bo;  off = p-256; }
    else if (p < 512)  { src = lns; off = p-384; }
    else if (p < 640)  { src = lnb; off = p-512; }
    else if (p < 1152) { src = b1;  off = p-640; }
    else if (p < 1280) { src = b2;  off = p-1152; }
    else               { src = gm;  off = p-1280; }
    PRM[p] = ldb(src, off, f32);
  }
}

// ---------------- K1: dual GEMM  gate = x@Wg+bg, hidden = x@Wh+bh (f16 out) ----------------
// Output layout [b][hw][c][t16]: per (mat,nt) store, the wave's 64 lanes write ONE dense
// 512B region (16 channels x 16 t) -> fully coalesced (was 16 scattered 32B fragments).
__global__ __launch_bounds__(256) void k1_dualgemm(
    const u16* __restrict__ XB, const u16* __restrict__ WgT, const u16* __restrict__ WhT,
    const u16* __restrict__ PRM,
    u16* __restrict__ GP, u16* __restrict__ HP)
{
  int bid = blockIdx.x;                  // 1568 = 2b * 784 hw-groups
  int b = bid / 784; int hw = (bid % 784)*4 + (threadIdx.x >> 6);
  int lane = threadIdx.x & 63;
  int lrow = lane & 15, q = lane >> 4;

  bf16x8 a[4];   // A row (in-tile) = lrow = t; k-cols q*8 + kt*32
  const u16* xr = XB + ((size_t)(b*16 + lrow)*3136 + hw)*128 + q*8;
#pragma unroll
  for (int kt = 0; kt < 4; ++kt) a[kt] = *(const bf16x8*)(xr + kt*32);

  size_t obase = ((size_t)(b*3136 + hw))*2048;   // *128 c *16 t

#pragma unroll
  for (int mat = 0; mat < 2; ++mat){
    const u16* WT  = mat ? WhT : WgT;
    const u16* bia = PRM + (mat ? 128 : 0);
    u16* out       = mat ? HP  : GP;
#pragma unroll
    for (int nt = 0; nt < 8; ++nt){
      f32x4 acc = {0.f,0.f,0.f,0.f};
      const u16* wr = WT + (nt*16 + lrow)*128 + q*8;
#pragma unroll
      for (int kt = 0; kt < 4; ++kt){
        bf16x8 bfr = *(const bf16x8*)(wr + kt*32);
        acc = MFMA16(a[kt], bfr, acc);
      }
      int c = nt*16 + lrow;              // C col = output channel
      float bv = b2f(bia[c]);
      ushort4 pk;
      pk.x = f2h(acc[0] + bv); pk.y = f2h(acc[1] + bv);
      pk.z = f2h(acc[2] + bv); pk.w = f2h(acc[3] + bv);
      *(ushort4*)(out + obase + (size_t)c*16 + q*4) = pk;   // t = q*4 .. q*4+3
    }
  }
}

// ---------------- K2: circular 5x7x7 depthwise conv via MFMA circulants + linear scan ----------------
__global__ __launch_bounds__(256, 5) void k2_conv_scan(
    const u16* __restrict__ GP, const u16* __restrict__ HP,
    const u16* __restrict__ CIRG, const u16* __restrict__ CIRH,
    u16* __restrict__ ELH)
{
  __shared__ __align__(16) unsigned su[6272];   // 25,088 B

  int bid = blockIdx.x;                    // 3136 = 2 * 32 * 49
  int b = bid / 1568; int rr = bid - b*1568;
  int cg = rr / 49; int s = rr % 49;
  int th = s / 7, tw = s % 7;
  int tid = threadIdx.x;
  int h0g = th*8, w0g = tw*8;
  size_t tbe = (size_t)(b*32 + cg)*200704;  // ELH u16 slab base (old layout)

  int wv = tid >> 6, lane = tid & 63;
  int q = lane >> 4, lrow = lane & 15;
  int hb = lrow >> 3, wb = lrow & 7;       // spatial of A-row at m=0: h=hb, w=wb

  int cu = __builtin_amdgcn_readfirstlane(cg*4 + wv);
  const u16* cirg = CIRG + (size_t)cu*12800;   // 25 tp * 64 lane * 8 u16
  const u16* cirh = CIRH + (size_t)cu*12800;

  // ---- staging chunk offsets: chunk ci = cl*392 + pos*2 + half  (LDS addr = ci*16, linear) ----
  // global src (new GP layout [b][hw][c][t]): byte = (hw*128 + cg*4 + cl)*32 + half*16
  unsigned soff[7]; bool sval[7];
#pragma unroll
  for (int ss = 0; ss < 7; ++ss){
    int ci = ss*256 + tid;
    sval[ss] = (ci < 1568);
    int clc = ci / 392;
    int rem = ci - clc*392;
    int pos = rem >> 1, half = rem & 1;
    int hh = pos / 14, ww = pos - hh*14;
    int hg = h0g + hh - 3; if (hg < 0) hg += 56; else if (hg >= 56) hg -= 56;
    int wg = w0g + ww - 3; if (wg < 0) wg += 56; else if (wg >= 56) wg -= 56;
    soff[ss] = (unsigned)(((hg*56 + wg)*128 + cg*4 + clc)*32 + half*16);
  }
  const char* gpb = (const char*)(GP + (size_t)b*6422528);
  const char* hpb = (const char*)(HP + (size_t)b*6422528);

  auto stagepass = [&](const char* Pb){
#pragma unroll
    for (int ss = 0; ss < 7; ++ss){
      if (sval[ss])
        gld_lds16(Pb + soff[ss], (char*)su + (ss*256 + wv*64)*16);
    }
  };

  auto convpass = [&](const u16* cir, f32x4* acc){
#pragma unroll
    for (int m = 0; m < 4; ++m) acc[m] = (f32x4){0.f,0.f,0.f,0.f};
    U4F bq0, bq1, bq2;
    bq0.u = *(const uint4*)(cir + 0*512 + lane*8);
    bq1.u = *(const uint4*)(cir + 1*512 + lane*8);
    bq2.u = *(const uint4*)(cir + 2*512 + lane*8);
    const int base_cl = wv*6272;
#pragma unroll
    for (int tp = 0; tp < 25; ++tp){
      const int tA = 2*tp;
      const int tB = (2*tp + 1 > 48) ? 48 : 2*tp + 1;
      const int dhA = 6 - tA/7, dwA = 6 - tA%7;
      const int dhB = 6 - tB/7, dwB = 6 - tB%7;
      int dh = (q >= 2) ? dhB : dhA;
      int dw = (q >= 2) ? dwB : dwA;
      const char* sp = (const char*)su +
          (base_cl + ((hb + dh)*14 + (wb + dw))*32 + (q & 1)*16);
      U4F a0, a1, a2, a3;
      a0.u = *(const uint4*)(sp);
      a1.u = *(const uint4*)(sp + 896);    // m=1: h += 2 -> pos += 28
      a2.u = *(const uint4*)(sp + 1792);
      a3.u = *(const uint4*)(sp + 2688);
      f16x8 bb = (tp % 3 == 0) ? bq0.h : (tp % 3 == 1) ? bq1.h : bq2.h;
      acc[0] = MFMAF16(a0.h, bb, acc[0]);
      acc[1] = MFMAF16(a1.h, bb, acc[1]);
      acc[2] = MFMAF16(a2.h, bb, acc[2]);
      acc[3] = MFMAF16(a3.h, bb, acc[3]);
      if (tp + 3 < 25){
        uint4 nb = *(const uint4*)(cir + (tp+3)*512 + lane*8);
        if (tp % 3 == 0) bq0.u = nb; else if (tp % 3 == 1) bq1.u = nb; else bq2.u = nb;
      }
    }
  };

  f32x4 accG[4], accH[4];
  stagepass(gpb);
  __syncthreads();          // gld_lds data resident
  convpass(cirg, accG);
  __syncthreads();          // conv reads done before restage overwrites
  stagepass(hpb);
  __syncthreads();
  convpass(cirh, accH);

  // ---- pointwise (linear-space) ----
  float fv[16], vv[16];
#pragma unroll
  for (int e = 0; e < 16; ++e){
    float g  = accG[e>>2][e&3];
    float hc = accH[e>>2][e&3];
    float eg = __expf(g);
    float fr = __builtin_amdgcn_rcpf(1.f + eg);   // 1 - z = sigmoid(-g)
    float zz = 1.f - fr;                          // z = sigmoid(g), inf-safe
    fv[e] = fr;
    vv[e] = (hc*hc + 1e-6f) * zz;
  }
  // ---- inclusive scan over t (= lrow) within 16-lane groups ----
#pragma unroll
  for (int d = 1; d < 16; d <<= 1){
    bool ok = (lrow >= d);
#pragma unroll
    for (int e = 0; e < 16; ++e){
      float Lf = __shfl_up(fv[e], (unsigned)d, 16);
      float Lv = __shfl_up(vv[e], (unsigned)d, 16);
      Lf = ok ? Lf : 1.f;
      Lv = ok ? Lv : 0.f;
      vv[e] = fmaf(fv[e], Lv, vv[e]);
      fv[e] = fv[e] * Lf;
    }
  }
  // ---- store h = vv (bf16) ----
  size_t ob = tbe + (size_t)lrow*12544 + (size_t)(h0g*56 + w0g)*4 + wv;
#pragma unroll
  for (int e = 0; e < 16; ++e){
    int r = (e>>2)*16 + q*4 + (e&3);
    ELH[ob + (size_t)((r>>3)*56 + (r&7))*4] = f2b(vv[e]);
  }
}

// ---------------- K34: R5 v3 structure + shared W-frags across tiles + swizzled sH (R8, tied-best) ----------------
__global__ __launch_bounds__(256, 2) void k34_gemm_ln_mlp(
    const u16* __restrict__ ELH, const u16* __restrict__ WoT,
    const u16* __restrict__ W1T, const u16* __restrict__ W2T,
    const u16* __restrict__ PRM,
    const void* __restrict__ xraw, void* __restrict__ outv)
{
  __shared__ __align__(16) u16 smem[40960];   // 81,920 B
  u16* sW0 = smem;               // 16384 u16 (32 KB)
  u16* sW1 = smem + 16384;       // 16384 u16
  u16* sXp = smem;               // 2*64*136 = 17408 u16 (phase A only; dead before staging)
  u16* sH  = smem + 32768;       // 4 waves * 2 tiles * 1024 u16 (stride 64 + XOR swizzle)

  int bid = blockIdx.x;          // 784 = 2b * 8t2 * 49s
  int b = bid / 392; int rem = bid - b*392;
  int t2 = rem / 49; int s2 = rem - t2*49;
  int hw0 = s2 * 64;
  int tid = threadIdx.x;
  int wv = tid >> 6, lane = tid & 63;
  int lrow = lane & 15, q = lane >> 4;
  const bool f32io = input_is_f32(xraw);

  // ---- phase A: ssm_out = elh@Wo + bo, LayerNorm -> sXp (tiles A: t2, B: t2+8) ----
  {
    int hw = hw0 + wv*16 + lrow;
    size_t tbA = ((size_t)(b*512) + t2)*3136;      // ((b*32+0)*16 + t2)*3136
    size_t tbB = tbA + (size_t)8*3136;
    union Cvt { uint4 u; bf16x8 v; };
    bf16x8 eA[4], eB[4];
#pragma unroll
    for (int kt = 0; kt < 4; ++kt){
      int cg0 = kt*8 + q*2;
      size_t eoA = (tbA + (size_t)cg0*50176 + hw)*4;
      size_t eoB = (tbB + (size_t)cg0*50176 + hw)*4;
      uint2 lo = *(const uint2*)(ELH + eoA);
      uint2 hi = *(const uint2*)(ELH + eoA + (size_t)50176*4);
      Cvt c1; c1.u = make_uint4(lo.x, lo.y, hi.x, hi.y); eA[kt] = c1.v;
      uint2 lo2 = *(const uint2*)(ELH + eoB);
      uint2 hi2 = *(const uint2*)(ELH + eoB + (size_t)50176*4);
      Cvt c2; c2.u = make_uint4(lo2.x, lo2.y, hi2.x, hi2.y); eB[kt] = c2.v;
    }

    float vA[8][4], vB[8][4];
#pragma unroll
    for (int nt = 0; nt < 8; ++nt){
      f32x4 aacc = {0.f,0.f,0.f,0.f}, bacc = {0.f,0.f,0.f,0.f};
      const u16* wr = WoT + (nt*16 + lrow)*128 + q*8;
#pragma unroll
      for (int kt = 0; kt < 4; ++kt){
        bf16x8 bfr = *(const bf16x8*)(wr + kt*32);
        aacc = MFMA16(eA[kt], bfr, aacc);
        bacc = MFMA16(eB[kt], bfr, bacc);
      }
      float bv = b2f(PRM[256 + nt*16 + lrow]);
#pragma unroll
      for (int i = 0; i < 4; ++i){ vA[nt][i] = aacc[i] + bv; vB[nt][i] = bacc[i] + bv; }
    }

#pragma unroll
    for (int i = 0; i < 4; ++i){
      float smA=0.f, sqA=0.f, smB=0.f, sqB=0.f;
#pragma unroll
      for (int nt = 0; nt < 8; ++nt){
        float a_ = vA[nt][i]; smA += a_; sqA = fmaf(a_, a_, sqA);
        float b_ = vB[nt][i]; smB += b_; sqB = fmaf(b_, b_, sqB);
      }
#pragma unroll
      for (int m = 1; m < 16; m <<= 1){
        smA += __shfl_xor(smA, m, 64); sqA += __shfl_xor(sqA, m, 64);
        smB += __shfl_xor(smB, m, 64); sqB += __shfl_xor(sqB, m, 64);
      }
      float mA = smA*(1.f/128.f), rA = rsqrtf(sqA*(1.f/128.f) - mA*mA + 1e-6f);
      float mB = smB*(1.f/128.f), rB = rsqrtf(sqB*(1.f/128.f) - mB*mB + 1e-6f);
      int r = wv*16 + q*4 + i;
#pragma unroll
      for (int nt = 0; nt < 8; ++nt){
        int c = nt*16 + lrow;
        float ls = b2f(PRM[384 + c]), lb = b2f(PRM[512 + c]);
        sXp[r*136 + c]        = f2b((vA[nt][i] - mA)*rA*ls + lb);
        sXp[8704 + r*136 + c] = f2b((vB[nt][i] - mB)*rB*ls + lb);
      }
    }
  }

  // a-frags: rows written by this same wave -> readable without barrier
  bf16x8 aA[4], aB[4];
#pragma unroll
  for (int kt = 0; kt < 4; ++kt){
    aA[kt] = *(const bf16x8*)&sXp[(wv*16 + lrow)*136 + kt*32 + q*8];
    aB[kt] = *(const bf16x8*)&sXp[8704 + (wv*16 + lrow)*136 + kt*32 + q*8];
  }
  __syncthreads();   // all waves done with sXp before W staging overwrites it

  // per-thread W-tile global srcs (nt advance: W1 part +8192, W2 part +64)
  const u16* wsrc[8];
#pragma unroll
  for (int r = 0; r < 8; ++r){
    int c = r*4 + wv;
    if (c < 16){
      int j = c >> 2, kt = c & 3;
      wsrc[r] = W1T + (size_t)(j*16 + lrow)*128 + kt*32 + q*8;
    } else {
      int c2 = c - 16; int jo = c2 >> 1, kt2 = c2 & 1;
      wsrc[r] = W2T + (size_t)(jo*16 + lrow)*512 + kt2*32 + q*8;
    }
  }
  auto stage = [&](u16* buf, int nt){
#pragma unroll
    for (int r = 0; r < 8; ++r){
      int c = r*4 + wv;
      const u16* src = wsrc[r] + (c < 16 ? (size_t)nt*8192 : (size_t)nt*64);
      gld_lds16(src, buf + c*512);            // dest wave-uniform; HW adds lane*16B
    }
  };

  f32x4 accA[8], accB[8];
#pragma unroll
  for (int jo = 0; jo < 8; ++jo){ accA[jo] = (f32x4){0.f,0.f,0.f,0.f}; accB[jo] = (f32x4){0.f,0.f,0.f,0.f}; }
  u16* sHwA = sH + wv*2048;
  u16* sHwB = sHwA + 1024;

  stage(sW0, 0);
  asm volatile("s_waitcnt vmcnt(0)" ::: "memory");
  __builtin_amdgcn_s_barrier();

  auto mlpstep = [&](int nt, u16* wcur, u16* wnxt, bool do_stage){
    if (do_stage) stage(wnxt, nt+1);          // in flight under compute
    // ---- phase 1: H = gelu(XN @ W1tile + b1); each W1 frag read ONCE, used by A and B ----
#pragma unroll
    for (int js = 0; js < 4; ++js){
      f32x4 hcA = {0.f,0.f,0.f,0.f}, hcB = {0.f,0.f,0.f,0.f};
#pragma unroll
      for (int kt = 0; kt < 4; ++kt){
        bf16x8 f = *(const bf16x8*)&wcur[(js*4 + kt)*512 + lane*8];
        hcA = MFMA16(aA[kt], f, hcA);
        hcB = MFMA16(aB[kt], f, hcB);
      }
      float bv = b2f(PRM[640 + nt*64 + js*16 + lrow]);
#pragma unroll
      for (int i = 0; i < 4; ++i){
        int r = q*4 + i;
        int cidx = (js*16 + lrow) ^ ((r & 7) << 3);   // 8-u16 granule XOR swizzle
        float vA_ = hcA[i] + bv;
        float uA = 0.79788456080286535588f*(vA_ + 0.044715f*vA_*vA_*vA_);
        float sA = __expf(-2.f*uA);
        sHwA[r*64 + cidx] = (u16)(__float_as_uint(vA_ * __builtin_amdgcn_rcpf(1.f + sA)) >> 16);
        float vB_ = hcB[i] + bv;
        float uB = 0.79788456080286535588f*(vB_ + 0.044715f*vB_*vB_*vB_);
        float sB = __expf(-2.f*uB);
        sHwB[r*64 + cidx] = (u16)(__float_as_uint(vB_ * __builtin_amdgcn_rcpf(1.f + sB)) >> 16);
      }
    }
    // ---- phase 2: acc += H @ W2tile; each W2 frag read ONCE, used by A and B ----
#pragma unroll
    for (int kt2 = 0; kt2 < 2; ++kt2){
      int hoff = (kt2*32 + q*8) ^ ((lrow & 7) << 3);
      bf16x8 afA = *(const bf16x8*)&sHwA[lrow*64 + hoff];
      bf16x8 afB = *(const bf16x8*)&sHwB[lrow*64 + hoff];
#pragma unroll
      for (int jo = 0; jo < 8; ++jo){
        bf16x8 f = *(const bf16x8*)&wcur[(16 + jo*2 + kt2)*512 + lane*8];
        accA[jo] = MFMA16(afA, f, accA[jo]);
        accB[jo] = MFMA16(afB, f, accB[jo]);
      }
    }
    asm volatile("s_waitcnt vmcnt(0)" ::: "memory");   // staged tile landed
    __builtin_amdgcn_s_barrier();
  };

  for (int nt2 = 0; nt2 < 4; ++nt2){
    mlpstep(2*nt2,     sW0, sW1, true);
    mlpstep(2*nt2 + 1, sW1, sW0, nt2 < 3);
  }

  // ---- epilogue: out = (acc + b2)*gamma + x  (both tiles) ----
  size_t rowA0 = ((size_t)(b*16 + t2))*3136 + hw0 + wv*16 + q*4;
  size_t rowB0 = rowA0 + (size_t)8*3136;
#pragma unroll
  for (int jo = 0; jo < 8; ++jo){
    int c = jo*16 + lrow;
    float bv  = b2f(PRM[1152 + c]);
    float gmv = b2f(PRM[1280 + c]);
#pragma unroll
    for (int i = 0; i < 4; ++i){
      size_t rA = rowA0 + i, rB = rowB0 + i;
      float yA = accA[jo][i] + bv, yB = accB[jo][i] + bv;
      if (f32io){
        float resA = ((const float*)xraw)[rA*128 + c];
        float resB = ((const float*)xraw)[rB*128 + c];
        ((float*)outv)[rA*128 + c] = yA*gmv + resA;
        ((float*)outv)[rB*128 + c] = yB*gmv + resB;
      } else {
        float resA = b2f(((const u16*)xraw)[rA*128 + c]);
        float resB = b2f(((const u16*)xraw)[rB*128 + c]);
        ((u16*)outv)[rA*128 + c] = f2b(yA*gmv + resA);
        ((u16*)outv)[rB*128 + c] = f2b(yB*gmv + resB);
      }
    }
  }
}

// ---------------- launch ----------------
extern "C" void kernel_launch(void* const* d_in, const int* in_sizes, int n_in,
                              void* d_out, int out_size, void* d_ws, size_t ws_size,
                              hipStream_t stream)
{
  const void* x   = d_in[0];
  const void* Wg  = d_in[1];
  const void* bg  = d_in[2];
  const void* Wh  = d_in[3];
  const void* bh  = d_in[4];
  const void* gk  = d_in[5];
  const void* hk  = d_in[6];
  const void* Wo  = d_in[7];
  const void* bo  = d_in[8];
  const void* lns = d_in[9];
  const void* lnb = d_in[10];
  const void* W1  = d_in[11];
  const void* b1  = d_in[12];
  const void* W2  = d_in[13];
  const void* b2  = d_in[14];
  const void* gm  = d_in[15];

  char* ws = (char*)d_ws;
  u16* GP  = (u16*)(ws + 0);              // 25,690,112 B each (f16)
  u16* HP  = (u16*)(ws + 25690112);
  u16* ELH = (u16*)(ws + 51380224);       // bf16
  u16* XB  = (u16*)(ws + 77070336);       // canonical bf16 x
  u16* WgT = (u16*)(ws + 102760448);
  u16* WhT = WgT + 16384;
  u16* WoT = WhT + 16384;
  u16* W1T = WoT + 16384;
  u16* W2T = W1T + 65536;
  unsigned* CIRG = (unsigned*)(W2T + 65536);   // 819,200 u32 = 3,276,800 B each
  unsigned* CIRH = CIRG + 819200;
  u16* PRM = (u16*)(CIRH + 819200);

  k0_prep        <<<dim3(512),  dim3(256), 0, stream>>>(x, Wg, Wh, Wo, W1, W2, gk, hk,
                                                        bg, bh, bo, lns, lnb, b1, b2, gm,
                                                        XB, WgT, WhT, WoT, W1T, W2T, CIRG, CIRH, PRM);
  k1_dualgemm    <<<dim3(1568), dim3(256), 0, stream>>>(XB, WgT, WhT, PRM, GP, HP);
  k2_conv_scan   <<<dim3(3136), dim3(256), 0, stream>>>(GP, HP, (const u16*)CIRG, (const u16*)CIRH, ELH);
  k34_gemm_ln_mlp<<<dim3(784),  dim3(256), 0, stream>>>(ELH, WoT, W1T, W2T, PRM, x, (void*)d_out);
}